// Round 1
// baseline (75.272 us; speedup 1.0000x reference)
//
#include <hip/hip_runtime.h>

#define CHUNK    2048
#define NTHREADS 256
#define EPT      8   // elements per thread; CHUNK = NTHREADS * EPT

// constants from the reference
#define C_TREND   0.6f
#define C_DETAIL  0.85f
#define C_SPIKE_T 3.5f
#define C_SPIKE_D 0.35f
#define C_EPS     1e-6f

__device__ __forceinline__ float reflect_load(const float* __restrict__ rp, int g, int L) {
    if (g < 0) g = -g;
    else if (g >= L) g = 2 * L - 2 - g;
    return rp[g];
}

// ---- Pass stage 1: per-block partial sums of residual (r, r^2) in double ----
__global__ __launch_bounds__(NTHREADS) void reduce_kernel(
    const float* __restrict__ in, double* __restrict__ partials, int L, int bpr) {
    int row = blockIdx.x / bpr;
    int chunk = blockIdx.x % bpr;
    const float* rp = in + (size_t)row * L;
    int o = chunk * CHUNK + threadIdx.x * EPT;

    // need elements [o-2, o+10) -> load aligned window [o-4, o+12)
    float w[16];
    if (o >= 4 && o + 12 <= L) {
        const float4* p = reinterpret_cast<const float4*>(rp + o - 4);
        #pragma unroll
        for (int j = 0; j < 4; ++j) {
            float4 v = p[j];
            w[4*j+0] = v.x; w[4*j+1] = v.y; w[4*j+2] = v.z; w[4*j+3] = v.w;
        }
    } else {
        #pragma unroll
        for (int j = 0; j < 16; ++j) w[j] = reflect_load(rp, o - 4 + j, L);
    }

    double s = 0.0, s2 = 0.0;
    float s5 = w[2] + w[3] + w[4] + w[5] + w[6];
    #pragma unroll
    for (int k = 0; k < EPT; ++k) {
        float local = s5 * 0.2f;
        float r = w[4 + k] - local;
        s += (double)r;
        s2 = fma((double)r, (double)r, s2);
        if (k < EPT - 1) s5 += w[7 + k] - w[2 + k];
    }

    // wave (64) reduce, then cross-wave via LDS
    #pragma unroll
    for (int off = 32; off > 0; off >>= 1) {
        s  += __shfl_down(s, off);
        s2 += __shfl_down(s2, off);
    }
    __shared__ double lds[8];
    int wid = threadIdx.x >> 6;
    int lane = threadIdx.x & 63;
    if (lane == 0) { lds[wid * 2] = s; lds[wid * 2 + 1] = s2; }
    __syncthreads();
    if (threadIdx.x == 0) {
        double ts  = lds[0] + lds[2] + lds[4] + lds[6];
        double ts2 = lds[1] + lds[3] + lds[5] + lds[7];
        partials[(size_t)blockIdx.x * 2 + 0] = ts;
        partials[(size_t)blockIdx.x * 2 + 1] = ts2;
    }
}

// ---- Pass stage 2: per-row threshold from partials (deterministic order) ----
__global__ __launch_bounds__(NTHREADS) void finalize_kernel(
    const double* __restrict__ partials, float* __restrict__ thr, int L, int bpr) {
    int row = blockIdx.x;
    const double* p = partials + (size_t)row * bpr * 2;
    double s = 0.0, s2 = 0.0;
    for (int i = threadIdx.x; i < bpr; i += NTHREADS) {
        s  += p[2 * i + 0];
        s2 += p[2 * i + 1];
    }
    #pragma unroll
    for (int off = 32; off > 0; off >>= 1) {
        s  += __shfl_down(s, off);
        s2 += __shfl_down(s2, off);
    }
    __shared__ double lds[8];
    int wid = threadIdx.x >> 6;
    int lane = threadIdx.x & 63;
    if (lane == 0) { lds[wid * 2] = s; lds[wid * 2 + 1] = s2; }
    __syncthreads();
    if (threadIdx.x == 0) {
        double ts  = lds[0] + lds[2] + lds[4] + lds[6];
        double ts2 = lds[1] + lds[3] + lds[5] + lds[7];
        double n = (double)L;
        double var = (ts2 - ts * ts / n) / (n - 1.0);
        float stdv = (float)sqrt(fmax(var, 0.0));
        thr[row] = fmaxf(stdv, C_EPS) * C_SPIKE_T;
    }
}

// ---- Pass stage 3: elementwise apply ----
__global__ __launch_bounds__(NTHREADS) void apply_kernel(
    const float* __restrict__ in, float* __restrict__ out,
    const float* __restrict__ thr_arr, int L, int bpr) {
    int row = blockIdx.x / bpr;
    int chunk = blockIdx.x % bpr;
    const float* rp = in + (size_t)row * L;
    float* op = out + (size_t)row * L;
    int o = chunk * CHUNK + threadIdx.x * EPT;

    // need elements [o-5, o+13) for 11-tap slide -> load aligned [o-8, o+16)
    float w[24];
    if (o >= 8 && o + 16 <= L) {
        const float4* p = reinterpret_cast<const float4*>(rp + o - 8);
        #pragma unroll
        for (int j = 0; j < 6; ++j) {
            float4 v = p[j];
            w[4*j+0] = v.x; w[4*j+1] = v.y; w[4*j+2] = v.z; w[4*j+3] = v.w;
        }
    } else {
        #pragma unroll
        for (int j = 0; j < 24; ++j) w[j] = reflect_load(rp, o - 8 + j, L);
    }

    float thr = thr_arr[row];
    float s5  = w[6] + w[7] + w[8] + w[9] + w[10];
    float s11 = w[3] + w[4] + w[5] + w[6] + w[7] + w[8] + w[9] + w[10] + w[11] + w[12] + w[13];
    float res[EPT];
    #pragma unroll
    for (int k = 0; k < EPT; ++k) {
        float local = s5 * 0.2f;
        float trend = s11 * (1.0f / 11.0f);
        float x = w[8 + k];
        float r = x - local;
        r = (fabsf(r) > thr) ? r * C_SPIKE_D : r;
        res[k] = (1.0f - C_TREND) * local + C_TREND * trend + C_DETAIL * r;
        if (k < EPT - 1) { s5 += w[11 + k] - w[6 + k]; s11 += w[14 + k] - w[3 + k]; }
    }

    float4* q = reinterpret_cast<float4*>(op + o);
    q[0] = make_float4(res[0], res[1], res[2], res[3]);
    q[1] = make_float4(res[4], res[5], res[6], res[7]);
}

extern "C" void kernel_launch(void* const* d_in, const int* in_sizes, int n_in,
                              void* d_out, int out_size, void* d_ws, size_t ws_size,
                              hipStream_t stream) {
    const float* x = (const float*)d_in[0];
    float* outp = (float*)d_out;

    const int ROWS = 16;           // B*C = 4*4
    int total = in_sizes[0];
    int L = total / ROWS;          // 1048576
    int bpr = L / CHUNK;           // 512
    int nblocks = ROWS * bpr;      // 8192

    // workspace layout: [intermediate 64MB][partials 128KB][thr 64B]
    float* xp1 = (float*)d_ws;
    size_t inter_bytes = (size_t)total * sizeof(float);
    double* partials = (double*)((char*)d_ws + inter_bytes);
    float* thr = (float*)((char*)d_ws + inter_bytes + (size_t)nblocks * 2 * sizeof(double));

    // pass 1: x -> xp1
    reduce_kernel<<<nblocks, NTHREADS, 0, stream>>>(x, partials, L, bpr);
    finalize_kernel<<<ROWS, NTHREADS, 0, stream>>>(partials, thr, L, bpr);
    apply_kernel<<<nblocks, NTHREADS, 0, stream>>>(x, xp1, thr, L, bpr);

    // pass 2: xp1 -> out
    reduce_kernel<<<nblocks, NTHREADS, 0, stream>>>(xp1, partials, L, bpr);
    finalize_kernel<<<ROWS, NTHREADS, 0, stream>>>(partials, thr, L, bpr);
    apply_kernel<<<nblocks, NTHREADS, 0, stream>>>(xp1, outp, thr, L, bpr);
}